// Round 2
// baseline (892.645 us; speedup 1.0000x reference)
//
#include <hip/hip_runtime.h>

#define WIN 5
#define WW 25          // 5*5
#define DF 64          // fine channels
#define DC 256         // coarse channels
#define HF 240
#define WF 320
#define LC 4800
#define NQ 16384
#define BS_STRIDE_F ((size_t)DF * HF * WF)   // per-batch stride of feat_f
#define CH_STRIDE   ((size_t)HF * WF)        // per-channel stride of feat_f

__global__ __launch_bounds__(256) void fine_preprocess_kernel(
    const float* __restrict__ f0, const float* __restrict__ f1,
    const float* __restrict__ c0, const float* __restrict__ c1,
    const float* __restrict__ Wd, const float* __restrict__ bd,
    const float* __restrict__ Wm, const float* __restrict__ bm,
    const int* __restrict__ b_ids, const int* __restrict__ cy,
    const int* __restrict__ cx,  const int* __restrict__ ci,
    float* __restrict__ out)
{
    const int n = blockIdx.x;          // query
    const int s = blockIdx.y;          // stream 0/1
    const int t = threadIdx.x;         // 0..255

    const int b  = b_ids[n];
    const int Y  = cy[n];
    const int X  = cx[n];
    const int cix = ci[n];

    const float* __restrict__ fc = s ? c1 : c0;
    const float* __restrict__ ff = s ? f1 : f0;

    __shared__ float c_sh[DC];         // gathered coarse vector
    __shared__ float cwin_sh[DF];      // c @ Wd + bd
    __shared__ float cpart_sh[DF];     // bm + cwin @ Wm[64:128]
    __shared__ float wm_sh[DF][DF];    // Wm[0:64]  (16 KB)
    __shared__ float red_sh[256];

    // ---- stage coarse vector (coalesced 256 fp32) ----
    c_sh[t] = fc[((size_t)b * LC + cix) * DC + t];

    // ---- stage Wm top half into LDS (coalesced) ----
    for (int i = t; i < DF * DF; i += 256)
        wm_sh[i >> 6][i & 63] = Wm[i];
    __syncthreads();

    // ---- c_win = c @ Wd + bd : 4 partial sums of 64 k's each ----
    {
        const int j  = t & 63;
        const int kc = t >> 6;                 // k-chunk 0..3
        float acc = 0.f;
        const float* wd = Wd + (size_t)(kc * 64) * DF + j;
        #pragma unroll 8
        for (int k = 0; k < 64; ++k)
            acc += c_sh[kc * 64 + k] * wd[(size_t)k * DF];
        red_sh[t] = acc;
    }
    __syncthreads();
    if (t < DF) {
        cwin_sh[t] = red_sh[t] + red_sh[t + 64] + red_sh[t + 128] +
                     red_sh[t + 192] + bd[t];
    }
    __syncthreads();

    // ---- c_part = bm + cwin @ Wm[64:128]  (shared across all 25 windows) ----
    if (t < DF) {
        float acc = bm[t];
        #pragma unroll 8
        for (int i = 0; i < DF; ++i)
            acc += cwin_sh[i] * Wm[(size_t)(64 + i) * DF + t];
        cpart_sh[t] = acc;
    }
    __syncthreads();

    // ---- per-window: out[w,j] = c_part[j] + sum_i f[w,i] * Wm_top[i,j] ----
    const int j  = t & 63;     // output channel (lane)
    const int w0 = t >> 6;     // wave id: windows w0, w0+4, ...
    const size_t fbase = (size_t)b * BS_STRIDE_F;
    const size_t obase = ((size_t)s * NQ + n) * (size_t)(WW * DF);

    for (int w = w0; w < WW; w += 4) {
        const int y = Y + (w / WIN) - (WIN / 2);
        const int x = X + (w % WIN) - (WIN / 2);
        const float* fp = ff + fbase + (size_t)y * WF + x;
        float acc = cpart_sh[j];
        #pragma unroll 8
        for (int i = 0; i < DF; ++i)
            acc += fp[(size_t)i * CH_STRIDE] * wm_sh[i][j];
        out[obase + (size_t)w * DF + j] = acc;
    }
}

extern "C" void kernel_launch(void* const* d_in, const int* in_sizes, int n_in,
                              void* d_out, int out_size, void* d_ws, size_t ws_size,
                              hipStream_t stream) {
    const float* f0 = (const float*)d_in[0];
    const float* f1 = (const float*)d_in[1];
    const float* c0 = (const float*)d_in[2];
    const float* c1 = (const float*)d_in[3];
    const float* Wd = (const float*)d_in[4];
    const float* bd = (const float*)d_in[5];
    const float* Wm = (const float*)d_in[6];
    const float* bm = (const float*)d_in[7];
    const int* b_ids = (const int*)d_in[8];
    const int* cyv   = (const int*)d_in[9];
    const int* cxv   = (const int*)d_in[10];
    const int* civ   = (const int*)d_in[11];
    float* out = (float*)d_out;

    dim3 grid(NQ, 2);
    dim3 block(256);
    fine_preprocess_kernel<<<grid, block, 0, stream>>>(
        f0, f1, c0, c1, Wd, bd, Wm, bm, b_ids, cyv, cxv, civ, out);
}

// Round 3
// 561.091 us; speedup vs baseline: 1.5909x; 1.5909x over previous
//
#include <hip/hip_runtime.h>

#define WIN 5
#define WW 25
#define DF 64
#define DC 256
#define HF 240
#define WF 320
#define LC 4800
#define NQ 16384
#define CH_STRIDE ((size_t)HF * WF)
#define BS_STRIDE_F ((size_t)DF * CH_STRIDE)
#define FPAD 68                 // padded LDS window row stride (17*16B aligned)

// d_ws float-index layout
#define WS_WFUSED 0             // 256*64 floats
#define WS_BFUSED (DC * DF)     // 64 floats (+pad)
#define WS_CPART  (DC * DF + 256)  // 32768*64 floats  (~8.4 MB total)

// ---------------- K0: Wfused = Wd @ Wm_bot,  bfused = bm + bd @ Wm_bot ----
__global__ __launch_bounds__(64) void k0_fuse_weights(
    const float* __restrict__ Wd, const float* __restrict__ bd,
    const float* __restrict__ Wm, const float* __restrict__ bm,
    float* __restrict__ ws)
{
    const int r = blockIdx.x;      // 0..255 -> Wfused row; 256 -> bfused
    const int j = threadIdx.x;     // 0..63
    if (r < DC) {
        float acc = 0.f;
        #pragma unroll 8
        for (int i = 0; i < DF; ++i)
            acc += Wd[r * DF + i] * Wm[(DF + i) * DF + j];
        ws[WS_WFUSED + r * DF + j] = acc;
    } else {
        float acc = bm[j];
        #pragma unroll 8
        for (int i = 0; i < DF; ++i)
            acc += bd[i] * Wm[(DF + i) * DF + j];
        ws[WS_BFUSED + j] = acc;
    }
}

// ---------------- K1: cpart[row][j] = bfused[j] + c[row] . Wfused[:,j] -----
// row = s*NQ + n ; c[row] = feat_c{s}[b_ids[n], ci_ids[n], :]
#define K1_ROWS 16
__global__ __launch_bounds__(256) void k1_cpart(
    const float* __restrict__ c0, const float* __restrict__ c1,
    const int* __restrict__ b_ids, const int* __restrict__ ci,
    float* __restrict__ ws)
{
    const float* __restrict__ wfused = ws + WS_WFUSED;
    const float* __restrict__ bfused = ws + WS_BFUSED;
    float* __restrict__ cpart = ws + WS_CPART;

    const int t  = threadIdx.x;
    const int j  = t & 63;         // output channel
    const int kc = t >> 6;         // K-quarter 0..3

    // register-cache this thread's Wfused quarter-column (coalesced, L2-hot)
    float wf[64];
    #pragma unroll
    for (int k = 0; k < 64; ++k)
        wf[k] = wfused[(kc * 64 + k) * DF + j];

    __shared__ float c_sh[DC];
    __shared__ float red[256];

    for (int ri = 0; ri < K1_ROWS; ++ri) {
        const int row = blockIdx.x * K1_ROWS + ri;
        const int s = row >> 14;
        const int n = row & (NQ - 1);
        const float* __restrict__ fc = s ? c1 : c0;
        const int b  = b_ids[n];
        const int cc = ci[n];

        c_sh[t] = fc[((size_t)b * LC + cc) * DC + t];   // coalesced stage
        __syncthreads();

        float acc = 0.f;
        #pragma unroll
        for (int k4 = 0; k4 < 16; ++k4) {
            float4 cv = *(const float4*)&c_sh[kc * 64 + k4 * 4];
            acc += cv.x * wf[k4 * 4 + 0] + cv.y * wf[k4 * 4 + 1] +
                   cv.z * wf[k4 * 4 + 2] + cv.w * wf[k4 * 4 + 3];
        }
        red[t] = acc;
        __syncthreads();

        if (t < 64) {
            cpart[(size_t)row * DF + t] =
                red[t] + red[t + 64] + red[t + 128] + red[t + 192] + bfused[t];
        }
        // next-iter __syncthreads orders red reads before next red writes
    }
}

// ---------------- K2: main — wave per (n,s), LDS window, reg-tiled GEMM ----
__global__ __launch_bounds__(256) void k2_main(
    const float* __restrict__ f0, const float* __restrict__ f1,
    const float* __restrict__ Wm,
    const int* __restrict__ b_ids, const int* __restrict__ cy,
    const int* __restrict__ cx,
    const float* __restrict__ ws, float* __restrict__ out)
{
    const float* __restrict__ cpart = ws + WS_CPART;

    const int t    = threadIdx.x;
    const int lane = t & 63;
    const int wave = t >> 6;

    __shared__ float wm_sh[DF * DF];            // Wm top half, [i][j], 16 KB
    __shared__ float f_sh[4 * WW * FPAD];       // per-wave window tiles, 27.2 KB

    // ---- stage Wm[0:64] (block-cooperative, coalesced float4) ----
    {
        const float4* src = (const float4*)Wm;
        float4* dst = (float4*)wm_sh;
        #pragma unroll
        for (int q = 0; q < 4; ++q)
            dst[t + q * 256] = src[t + q * 256];
    }

    // ---- wave-private window gather: 25 coalesced loads ----
    const int gw = blockIdx.x * 4 + wave;       // 0..32767 = s*NQ + n
    const int s  = gw >> 14;
    const int n  = gw & (NQ - 1);
    const float* __restrict__ ff = s ? f1 : f0;
    const int b = b_ids[n];
    const int Y = cy[n];
    const int X = cx[n];

    float* fw = f_sh + wave * WW * FPAD;
    const float* fwin = ff + (size_t)b * BS_STRIDE_F + (size_t)(Y - 2) * WF + (X - 2);
    #pragma unroll
    for (int r = 0; r < 25; ++r) {
        const int e = lane + r * 64;            // 0..1599
        const int i = e / 25;                   // channel
        const int w = e - i * 25;               // window pos
        const int wy = w / 5;
        const int wx = w - wy * 5;
        fw[w * FPAD + i] = fwin[(size_t)i * CH_STRIDE + wy * WF + wx];
    }
    __syncthreads();

    // ---- compute: out[w][j] = cpart[j] + sum_i f[w][i]*wm[i][j] ----
    const int j0 = (lane & 15) * 4;             // 4 output channels
    const int w0 = lane >> 4;                   // window group: w = w0 + 4u

    const float4 cp = *(const float4*)&cpart[(size_t)gw * DF + j0];
    float4 acc[7];
    #pragma unroll
    for (int u = 0; u < 7; ++u) acc[u] = cp;

    #pragma unroll 4
    for (int i = 0; i < DF; i += 4) {
        const float4 m0 = *(const float4*)&wm_sh[(i + 0) * DF + j0];
        const float4 m1 = *(const float4*)&wm_sh[(i + 1) * DF + j0];
        const float4 m2 = *(const float4*)&wm_sh[(i + 2) * DF + j0];
        const float4 m3 = *(const float4*)&wm_sh[(i + 3) * DF + j0];
        #pragma unroll
        for (int u = 0; u < 7; ++u) {
            const int w = w0 + 4 * u;
            if (w < WW) {
                const float4 fv = *(const float4*)&fw[w * FPAD + i];
                acc[u].x += fv.x * m0.x + fv.y * m1.x + fv.z * m2.x + fv.w * m3.x;
                acc[u].y += fv.x * m0.y + fv.y * m1.y + fv.z * m2.y + fv.w * m3.y;
                acc[u].z += fv.x * m0.z + fv.y * m1.z + fv.z * m2.z + fv.w * m3.z;
                acc[u].w += fv.x * m0.w + fv.y * m1.w + fv.z * m2.w + fv.w * m3.w;
            }
        }
    }

    // ---- store ----
    float* ob = out + (size_t)gw * (WW * DF);
    #pragma unroll
    for (int u = 0; u < 7; ++u) {
        const int w = w0 + 4 * u;
        if (w < WW)
            *(float4*)&ob[w * DF + j0] = acc[u];
    }
}

extern "C" void kernel_launch(void* const* d_in, const int* in_sizes, int n_in,
                              void* d_out, int out_size, void* d_ws, size_t ws_size,
                              hipStream_t stream) {
    const float* f0 = (const float*)d_in[0];
    const float* f1 = (const float*)d_in[1];
    const float* c0 = (const float*)d_in[2];
    const float* c1 = (const float*)d_in[3];
    const float* Wd = (const float*)d_in[4];
    const float* bd = (const float*)d_in[5];
    const float* Wm = (const float*)d_in[6];
    const float* bm = (const float*)d_in[7];
    const int* b_ids = (const int*)d_in[8];
    const int* cyv   = (const int*)d_in[9];
    const int* cxv   = (const int*)d_in[10];
    const int* civ   = (const int*)d_in[11];
    float* out = (float*)d_out;
    float* ws  = (float*)d_ws;

    k0_fuse_weights<<<dim3(DC + 1), dim3(64), 0, stream>>>(Wd, bd, Wm, bm, ws);
    k1_cpart<<<dim3(2 * NQ / K1_ROWS), dim3(256), 0, stream>>>(c0, c1, b_ids, civ, ws);
    k2_main<<<dim3(2 * NQ / 4), dim3(256), 0, stream>>>(f0, f1, Wm, b_ids, cyv, cxv, ws, out);
}